// Round 7
// baseline (348.876 us; speedup 1.0000x reference)
//
#include <hip/hip_runtime.h>

// LongTermMemoryMLP: 3 batched NT-GEMMs with per-batch weights.
//   h0 = relu(q  @ W0^T + b0)   [8,4096,512]x[8,1024,512]^T
//   h1 = relu(h0 @ W1^T + b1)   [8,4096,1024]x[8,1024,1024]^T
//   out =      h1 @ W2^T + b2   [8,4096,1024]x[8,512,1024]^T  (fp32 out)
// Round 10: occupancy attack. 7 rounds of intra-block scheduling all landed
// 81-102us with both pipes <45% (latency/sync-bound, not throughput). All ran
// 2 waves/SIMD. Now: 16 waves (1024 thr), wave tile 64x64, 4 waves/SIMD —
// every barrier/lgkm/vmcnt stall has other waves to run under (m114
// mechanism). mfma_f32_32x32x16_f16 (faster ceiling, half the instructions,
// acc = 64 regs -> <=128 VGPR = the 4-waves/SIMD requirement). Keeps the
// proven pieces: 256x256/BK=32/DEPTH-4 ring, counted vmcnt (4 steady, 4->2->0
// tail), zero-conflict XOR swizzle both-sides, XCD-chunked grid swizzle,
// clean barrier/vmwait primitives.

typedef _Float16 f16x8 __attribute__((ext_vector_type(8)));
typedef _Float16 f16x4 __attribute__((ext_vector_type(4)));
typedef float    f32x4 __attribute__((ext_vector_type(4)));
typedef float    f32x16 __attribute__((ext_vector_type(16)));

// async global->LDS DMA, 16B per lane; LDS dest = wave-uniform base + lane*16.
__device__ __forceinline__ void stage16(const void* g, void* l) {
    __builtin_amdgcn_global_load_lds(
        (const __attribute__((address_space(1))) unsigned int*)g,
        (__attribute__((address_space(3))) unsigned int*)l,
        16, 0, 0);
}

// counted VMEM wait: NO memory clobber (a clobber makes the waitcnt inserter
// treat the asm as a memory access and pre-drain it).
template <int CNT> __device__ __forceinline__ void vmwait() {
    if constexpr (CNT == 4)      asm volatile("s_waitcnt vmcnt(4)");
    else if constexpr (CNT == 2) asm volatile("s_waitcnt vmcnt(2)");
    else                         asm volatile("s_waitcnt vmcnt(0)");
}
// raw barrier: sched_barrier(0) pins earlier ds/stage ops before it; builtin
// s_barrier carries no implicit waitcnt.
__device__ __forceinline__ void barrier_() {
    __builtin_amdgcn_sched_barrier(0);
    __builtin_amdgcn_s_barrier();
}

// ---- fp32 -> f16 casts, all four arrays in one launch ----
__device__ __forceinline__ void cast_seg(const float* __restrict__ s,
                                         _Float16* __restrict__ d, int n4) {
    const int stride = gridDim.x * 256;
    for (int i = blockIdx.x * 256 + threadIdx.x; i < n4; i += stride) {
        float4 f = reinterpret_cast<const float4*>(s)[i];
        f16x4 o;
        o[0] = (_Float16)f.x; o[1] = (_Float16)f.y;
        o[2] = (_Float16)f.z; o[3] = (_Float16)f.w;
        reinterpret_cast<f16x4*>(d)[i] = o;
    }
}

__global__ __launch_bounds__(256) void cast_all(
    const float* s0, _Float16* d0, int n0,
    const float* s1, _Float16* d1, int n1,
    const float* s2, _Float16* d2, int n2,
    const float* s3, _Float16* d3, int n3) {
    cast_seg(s0, d0, n0);
    cast_seg(s1, d1, n1);
    cast_seg(s2, d2, n2);
    cast_seg(s3, d3, n3);
}

// ---- 16-wave all-f16 GEMM: C[b,m,n] = sum_k A[b,m,k]*W[b,n,k] + bias ----
// 256x256 tile, BK=32, 16 waves (4Mx4N), wave tile 64x64 =
// 2x2 x mfma_f32_32x32x16_f16 x 2 ksteps. LDS ring of 4 K-tiles (128 KiB).
// Per K-tile: {8 ds_read_b128 | 2 stage16 | barrier | 8 MFMA | wait | barrier}
// LDS 16B k-chunk XOR-swizzled by (row>>1)&3 on BOTH sides -> 0 conflicts.
// Grid: 1D, bijectively XCD-chunk-swizzled (nwg % 8 == 0 for all 3 GEMMs).
template <bool RELU, bool OUT_F16>
__global__ __launch_bounds__(1024, 4) void gemm_w16(
    const _Float16* __restrict__ A, const _Float16* __restrict__ W,
    const float* __restrict__ bias, void* __restrict__ Outv,
    int M, int N, int K) {
    constexpr int BM = 256, BN = 256, BK = 32;
    constexpr int DEPTH = 4;                       // K-tiles resident in LDS
    __shared__ __align__(16) _Float16 As[DEPTH][BM * BK];   // 4 x 16 KiB
    __shared__ __align__(16) _Float16 Bs[DEPTH][BN * BK];   // 4 x 16 KiB

    const int tid  = threadIdx.x;
    const int lane = tid & 63;
    const int l31  = lane & 31;          // row within 32x32 fragment
    const int kg   = lane >> 5;          // k-half within kstep (0/1)
    const int sx   = (l31 >> 1) & 3;     // per-thread swizzle key
    const int w    = tid >> 6;           // wave 0..15
    const int wm   = (w >> 2) * 64;      // 4 waves along M
    const int wn   = (w & 3) * 64;       // 4 waves along N

    // fragment read offsets (f16 units): row*BK + swizzled_chunk*8.
    // global chunk for kstep ks is ks*2+kg; stored at LDS chunk (ks*2+kg)^sx
    // (valid because row&7 == l31&7 for all fragment rows).
    const int kch0 = ((0 + kg) ^ sx) * 8;
    const int kch1 = ((2 + kg) ^ sx) * 8;
    const int aoffr0 = (wm +  0 + l31) * BK;
    const int aoffr1 = (wm + 32 + l31) * BK;
    const int boffr0 = (wn +  0 + l31) * BK;
    const int boffr1 = (wn + 32 + l31) * BK;

    // XCD-chunked bijective block swizzle (nwg % 8 == 0).
    const int nwg = gridDim.x;
    const int cpx = nwg >> 3;
    const int sw  = (blockIdx.x & 7) * cpx + (blockIdx.x >> 3);
    const int MB  = M >> 8;
    const int NB  = N >> 8;
    const int bm  = sw % MB;
    const int rr  = sw / MB;
    const int bn  = rr % NB;
    const int b   = rr / NB;

    // staging: thread stages A chunk tid and B chunk tid (1024 chunks = one
    // 256x32 tile each). LDS dest f16-offset 8*tid (linear — DMA constraint);
    // global source chunk is XOR-swizzled so LDS[row][kc] holds global chunk
    // kc^((row>>1)&3) — the involution the reads invert.
    const int srow = tid >> 2;
    const int skcg = (tid & 3) ^ ((srow >> 1) & 3);

    const char* Ab = (const char*)(A + (size_t)b * M * K + (size_t)(bm * BM) * K);
    const char* Wb = (const char*)(W + (size_t)b * N * K + (size_t)(bn * BN) * K);
    size_t goff = ((size_t)srow * K + skcg * 8) * 2;   // same for A and B
    constexpr size_t KSTEP = (size_t)BK * 2;           // byte advance per K-tile

    f32x16 acc[2][2];
#pragma unroll
    for (int mi = 0; mi < 2; ++mi)
#pragma unroll
        for (int ni = 0; ni < 2; ++ni)
            acc[mi][ni] = (f32x16){0.f, 0.f, 0.f, 0.f, 0.f, 0.f, 0.f, 0.f,
                                   0.f, 0.f, 0.f, 0.f, 0.f, 0.f, 0.f, 0.f};

    const int nk = K / BK;          // 16 or 32

    // prologue: stage tiles 0..2 (6 stage16/thread); wait tile 0 landed
    // (tiles 1,2 = 4 loads in flight).
#pragma unroll
    for (int p = 0; p < DEPTH - 1; ++p) {
        stage16(Ab + goff, &As[p][8 * (size_t)tid]);
        stage16(Wb + goff, &Bs[p][8 * (size_t)tid]);
        goff += KSTEP;
    }
    vmwait<4>();
    barrier_();

    for (int t = 0; t < nk; ++t) {
        const int slot = t & 3;

        // fragment reads for tile t (8 x ds_read_b128)
        f16x8 a00 = *(const f16x8*)(&As[slot][aoffr0 + kch0]);
        f16x8 a10 = *(const f16x8*)(&As[slot][aoffr1 + kch0]);
        f16x8 a01 = *(const f16x8*)(&As[slot][aoffr0 + kch1]);
        f16x8 a11 = *(const f16x8*)(&As[slot][aoffr1 + kch1]);
        f16x8 b00 = *(const f16x8*)(&Bs[slot][boffr0 + kch0]);
        f16x8 b10 = *(const f16x8*)(&Bs[slot][boffr1 + kch0]);
        f16x8 b01 = *(const f16x8*)(&Bs[slot][boffr0 + kch1]);
        f16x8 b11 = *(const f16x8*)(&Bs[slot][boffr1 + kch1]);

        // stage tile t+3 into the slot vacated at tile t-1
        if (t + 3 < nk) {
            const int ns = (t + 3) & 3;
            stage16(Ab + goff, &As[ns][8 * (size_t)tid]);
            stage16(Wb + goff, &Bs[ns][8 * (size_t)tid]);
            goff += KSTEP;
        }
        barrier_();

        __builtin_amdgcn_s_setprio(1);
        acc[0][0] = __builtin_amdgcn_mfma_f32_32x32x16_f16(a00, b00, acc[0][0], 0, 0, 0);
        acc[0][1] = __builtin_amdgcn_mfma_f32_32x32x16_f16(a00, b10, acc[0][1], 0, 0, 0);
        acc[1][0] = __builtin_amdgcn_mfma_f32_32x32x16_f16(a10, b00, acc[1][0], 0, 0, 0);
        acc[1][1] = __builtin_amdgcn_mfma_f32_32x32x16_f16(a10, b10, acc[1][1], 0, 0, 0);
        acc[0][0] = __builtin_amdgcn_mfma_f32_32x32x16_f16(a01, b01, acc[0][0], 0, 0, 0);
        acc[0][1] = __builtin_amdgcn_mfma_f32_32x32x16_f16(a01, b11, acc[0][1], 0, 0, 0);
        acc[1][0] = __builtin_amdgcn_mfma_f32_32x32x16_f16(a11, b01, acc[1][0], 0, 0, 0);
        acc[1][1] = __builtin_amdgcn_mfma_f32_32x32x16_f16(a11, b11, acc[1][1], 0, 0, 0);
        __builtin_amdgcn_s_setprio(0);

        // tile t+1 must be landed for all waves after this barrier.
        if (t + 3 < nk)      vmwait<4>();
        else if (t + 2 < nk) vmwait<2>();
        else if (t + 1 < nk) vmwait<0>();
        if (t + 1 < nk) barrier_();
    }

    // epilogue: bias (+relu), store.
    // 32x32 C/D: col = lane&31, row = (reg&3) + 8*(reg>>2) + 4*(lane>>5).
#pragma unroll
    for (int mi = 0; mi < 2; ++mi)
#pragma unroll
        for (int ni = 0; ni < 2; ++ni) {
            const float bc = bias[(size_t)b * N + bn * BN + wn + ni * 32 + l31];
            const size_t col = (size_t)bn * BN + wn + ni * 32 + l31;
            const int row0 = bm * BM + wm + mi * 32 + 4 * kg;
#pragma unroll
            for (int r = 0; r < 16; ++r) {
                const int rowr = row0 + (r & 3) + 8 * (r >> 2);
                const size_t ro = (size_t)b * M * N + (size_t)rowr * N + col;
                float v = acc[mi][ni][r] + bc;
                if (RELU) v = fmaxf(v, 0.f);
                if (OUT_F16)
                    ((_Float16*)Outv)[ro] = (_Float16)v;
                else
                    ((float*)Outv)[ro] = v;
            }
        }
}

// ---- legacy 2-barrier kernel, mixed f32/f16 operands (fallback path only) ----
__device__ __forceinline__ uint4 load8f32(const char* p) {
    const float4* fp = reinterpret_cast<const float4*>(p);
    float4 f0 = fp[0], f1 = fp[1];
    f16x8 o;
    o[0] = (_Float16)f0.x; o[1] = (_Float16)f0.y;
    o[2] = (_Float16)f0.z; o[3] = (_Float16)f0.w;
    o[4] = (_Float16)f1.x; o[5] = (_Float16)f1.y;
    o[6] = (_Float16)f1.z; o[7] = (_Float16)f1.w;
    return __builtin_bit_cast(uint4, o);
}

template <bool A_F16, bool W_F16, bool RELU, bool OUT_F16>
__global__ __launch_bounds__(256) void gemm_bias_act(
    const void* __restrict__ Av, const void* __restrict__ Wv,
    const float* __restrict__ bias, void* __restrict__ Outv,
    int M, int N, int K) {
    constexpr int BM = 128, BN = 128, BK = 32;
    __shared__ __align__(16) _Float16 As[BM * BK];
    __shared__ __align__(16) _Float16 Bs[BN * BK];

    const int tid  = threadIdx.x;
    const int lane = tid & 63;
    const int rowl = lane & 15;
    const int q8   = (lane >> 4) * 8;
    const int wm   = ((tid >> 6) >> 1) * 64;
    const int wn   = ((tid >> 6) & 1) * 64;
    const int bm = blockIdx.x, bn = blockIdx.y, b = blockIdx.z;

    const int c0 = tid, c1 = tid + 256;
    const int ar0 = c0 >> 2, ak0 = (c0 & 3) * 8;
    const int ar1 = c1 >> 2, ak1 = (c1 & 3) * 8;

    constexpr size_t esA = A_F16 ? 2 : 4;
    constexpr size_t esW = W_F16 ? 2 : 4;
    const char* Abase = (const char*)Av;
    const char* Wbase = (const char*)Wv;

    size_t aoff0 = ((size_t)b * M * K + (size_t)(bm * BM + ar0) * K + ak0) * esA;
    size_t aoff1 = ((size_t)b * M * K + (size_t)(bm * BM + ar1) * K + ak1) * esA;
    size_t woff0 = ((size_t)b * N * K + (size_t)(bn * BN + ar0) * K + ak0) * esW;
    size_t woff1 = ((size_t)b * N * K + (size_t)(bn * BN + ar1) * K + ak1) * esW;

    f32x4 acc[4][4];
#pragma unroll
    for (int mi = 0; mi < 4; ++mi)
#pragma unroll
        for (int ni = 0; ni < 4; ++ni)
            acc[mi][ni] = (f32x4){0.f, 0.f, 0.f, 0.f};

    const int nk = K / BK;
    for (int kk = 0; kk < nk; ++kk) {
        uint4 va0, va1, vw0, vw1;
        if (!A_F16) { va0 = load8f32(Abase + aoff0); va1 = load8f32(Abase + aoff1); }
        if (!W_F16) { vw0 = load8f32(Wbase + woff0); vw1 = load8f32(Wbase + woff1); }
        __syncthreads();
        if (A_F16) {
            stage16(Abase + aoff0, As + 8 * (size_t)c0);
            stage16(Abase + aoff1, As + 8 * (size_t)c1);
        } else {
            *(uint4*)(As + ar0 * BK + ak0) = va0;
            *(uint4*)(As + ar1 * BK + ak1) = va1;
        }
        if (W_F16) {
            stage16(Wbase + woff0, Bs + 8 * (size_t)c0);
            stage16(Wbase + woff1, Bs + 8 * (size_t)c1);
        } else {
            *(uint4*)(Bs + ar0 * BK + ak0) = vw0;
            *(uint4*)(Bs + ar1 * BK + ak1) = vw1;
        }
        aoff0 += BK * esA; aoff1 += BK * esA;
        woff0 += BK * esW; woff1 += BK * esW;
        __syncthreads();

        f16x8 af[4], bf[4];
#pragma unroll
        for (int i = 0; i < 4; ++i)
            af[i] = *(const f16x8*)(As + (wm + i * 16 + rowl) * BK + q8);
#pragma unroll
        for (int i = 0; i < 4; ++i)
            bf[i] = *(const f16x8*)(Bs + (wn + i * 16 + rowl) * BK + q8);
#pragma unroll
        for (int mi = 0; mi < 4; ++mi)
#pragma unroll
            for (int ni = 0; ni < 4; ++ni)
                acc[mi][ni] = __builtin_amdgcn_mfma_f32_16x16x32_f16(
                    af[mi], bf[ni], acc[mi][ni], 0, 0, 0);
    }

    const int q = lane >> 4;
    float bcol[4];
    {
        const float* bp = bias + (size_t)b * N + bn * BN + wn;
#pragma unroll
        for (int ni = 0; ni < 4; ++ni) bcol[ni] = bp[ni * 16 + rowl];
    }
#pragma unroll
    for (int mi = 0; mi < 4; ++mi) {
        const int row0 = bm * BM + wm + mi * 16 + q * 4;
#pragma unroll
        for (int r = 0; r < 4; ++r) {
            const size_t ro = (size_t)b * M * N + (size_t)(row0 + r) * N + bn * BN + wn;
#pragma unroll
            for (int ni = 0; ni < 4; ++ni) {
                float v = acc[mi][ni][r] + bcol[ni];
                if (RELU) v = fmaxf(v, 0.f);
                if (OUT_F16)
                    ((_Float16*)Outv)[ro + ni * 16 + rowl] = (_Float16)v;
                else
                    ((float*)Outv)[ro + ni * 16 + rowl] = v;
            }
        }
    }
}

extern "C" void kernel_launch(void* const* d_in, const int* in_sizes, int n_in,
                              void* d_out, int out_size, void* d_ws, size_t ws_size,
                              hipStream_t stream) {
    const int B = 8, S = 4096, DI = 512, DH = 1024, DO = 512;
    const float* query = (const float*)d_in[0];
    const float* W0    = (const float*)d_in[1];
    const float* b0    = (const float*)d_in[2];
    const float* W1    = (const float*)d_in[3];
    const float* b1    = (const float*)d_in[4];
    const float* W2    = (const float*)d_in[5];
    const float* b2    = (const float*)d_in[6];

    char* ws = (char*)d_ws;
    const size_t nH  = (size_t)B * S * DH;   // 33.5M
    const size_t nQ  = (size_t)B * S * DI;   // 16.8M
    const size_t nW0 = (size_t)B * DH * DI;  // 4.2M
    const size_t nW1 = (size_t)B * DH * DH;  // 8.4M
    const size_t nW2 = (size_t)B * DO * DH;  // 4.2M

    _Float16* h0 = (_Float16*)ws;             // 64 MiB
    _Float16* h1 = (_Float16*)(ws + nH * 2);  // 64 MiB
    const size_t off_casts = nH * 4;
    const size_t full_need = off_casts + (nQ + nW0 + nW1 + nW2) * 2;  // 192 MiB

    if (ws_size >= full_need) {
        _Float16* qf  = (_Float16*)(ws + off_casts);
        _Float16* w0f = qf + nQ;
        _Float16* w1f = w0f + nW0;
        _Float16* w2f = w1f + nW1;
        cast_all<<<dim3(2048), dim3(256), 0, stream>>>(
            query, qf, (int)(nQ / 4), W0, w0f, (int)(nW0 / 4),
            W1, w1f, (int)(nW1 / 4), W2, w2f, (int)(nW2 / 4));
        const dim3 blk(1024);
        // 1D swizzled grids: nwg = (S/256)*(N/256)*B, divisible by 8.
        const dim3 g0(dim3((S / 256) * (DH / 256) * B));   // 512
        const dim3 g2(dim3((S / 256) * (DO / 256) * B));   // 256
        gemm_w16<true,  true ><<<g0, blk, 0, stream>>>(qf, w0f, b0, h0, S, DH, DI);
        gemm_w16<true,  true ><<<g0, blk, 0, stream>>>(h0, w1f, b1, h1, S, DH, DH);
        gemm_w16<false, false><<<g2, blk, 0, stream>>>(h1, w2f, b2, d_out, S, DO, DH);
    } else {
        const dim3 blk(256);
        const dim3 g0(S / 128, DH / 128, B);
        const dim3 g2(S / 128, DO / 128, B);
        gemm_bias_act<false, false, true,  true ><<<g0, blk, 0, stream>>>(query, W0, b0, h0, S, DH, DI);
        gemm_bias_act<true,  false, true,  true ><<<g0, blk, 0, stream>>>(h0, W1, b1, h1, S, DH, DH);
        gemm_bias_act<true,  false, false, false><<<g2, blk, 0, stream>>>(h1, W2, b2, d_out, S, DO, DH);
    }
}

// Round 10
// 319.142 us; speedup vs baseline: 1.0932x; 1.0932x over previous
//
#include <hip/hip_runtime.h>

// LongTermMemoryMLP: 3 batched NT-GEMMs with per-batch weights.
//   h0 = relu(q  @ W0^T + b0)   [8,4096,512]x[8,1024,512]^T
//   h1 = relu(h0 @ W1^T + b1)   [8,4096,1024]x[8,1024,1024]^T
//   out =      h1 @ W2^T + b2   [8,4096,1024]x[8,512,1024]^T  (fp32 out)
// Round 13: third submission of the m201-style quadrant-phase kernel (two
// prior rounds died to container/infra failures with no kernel signal; three
// audits found no divergent barrier, no unsatisfiable wait, no OOB).
// BK=64, double-buffered LDS, 4 phases per K-tile, each phase =
// {front-loaded ds_reads | 2 per-wave-partitioned stage16 | barrier |
// 16 MFMA (one C-quadrant x K=64) | [counted vmcnt] | barrier}. Each wave
// stages ONLY the A-half/B-rows it consumes, ordered to match next-tile phase
// consumption (B k0,k1 @ph0; B k2,k3 @ph1; A k0,k1 @ph2; A k2,k3 @ph3), so
// boundary waits are vmcnt(4) (end-ph1) / vmcnt(2) (end-ph3) — never 0 in
// steady state, every wait drains loads >=2 phases old. Row stride 128B is
// the 16-way-conflict pathology -> slot XOR (ks*4+q)^(row&7) on BOTH sides
// (pre-swizzled global source for the linear DMA dest; same XOR on ds_read).
// Keeps XCD-chunked grid swizzle (FETCH -25%) + clean barrier/vmwait prims.

typedef _Float16 f16x8 __attribute__((ext_vector_type(8)));
typedef _Float16 f16x4 __attribute__((ext_vector_type(4)));
typedef float    f32x4 __attribute__((ext_vector_type(4)));

// async global->LDS DMA, 16B per lane; LDS dest = wave-uniform base + lane*16.
__device__ __forceinline__ void stage16(const void* g, void* l) {
    __builtin_amdgcn_global_load_lds(
        (const __attribute__((address_space(1))) unsigned int*)g,
        (__attribute__((address_space(3))) unsigned int*)l,
        16, 0, 0);
}

// counted VMEM wait: NO memory clobber (a clobber makes the waitcnt inserter
// treat the asm as a memory access and pre-drain it).
template <int CNT> __device__ __forceinline__ void vmwait() {
    if constexpr (CNT == 4)      asm volatile("s_waitcnt vmcnt(4)");
    else if constexpr (CNT == 2) asm volatile("s_waitcnt vmcnt(2)");
    else                         asm volatile("s_waitcnt vmcnt(0)");
}
// raw barrier: sched_barrier(0) pins earlier ds/stage ops before it; builtin
// s_barrier carries no implicit waitcnt.
__device__ __forceinline__ void barrier_() {
    __builtin_amdgcn_sched_barrier(0);
    __builtin_amdgcn_s_barrier();
}

// ---- fp32 -> f16 casts, all four arrays in one launch ----
__device__ __forceinline__ void cast_seg(const float* __restrict__ s,
                                         _Float16* __restrict__ d, int n4) {
    const int stride = gridDim.x * 256;
    for (int i = blockIdx.x * 256 + threadIdx.x; i < n4; i += stride) {
        float4 f = reinterpret_cast<const float4*>(s)[i];
        f16x4 o;
        o[0] = (_Float16)f.x; o[1] = (_Float16)f.y;
        o[2] = (_Float16)f.z; o[3] = (_Float16)f.w;
        reinterpret_cast<f16x4*>(d)[i] = o;
    }
}

__global__ __launch_bounds__(256) void cast_all(
    const float* s0, _Float16* d0, int n0,
    const float* s1, _Float16* d1, int n1,
    const float* s2, _Float16* d2, int n2,
    const float* s3, _Float16* d3, int n3) {
    cast_seg(s0, d0, n0);
    cast_seg(s1, d1, n1);
    cast_seg(s2, d2, n2);
    cast_seg(s3, d3, n3);
}

// ---- m201-style BK=64 dbuf GEMM: C[b,m,n] = sum_k A[b,m,k]*W[b,n,k]+bias --
// 256x256 tile, BK=64, 8 waves (2Mx4N), wave tile 128x64, 16x16x32 MFMA.
// LDS: 2 x (A[256][64] + B[256][64]) f16 = 128 KiB.
// Per K-tile: 4 phases; phase p computes quadrant (mh=p>>1, nh=p&1).
//   ph0: read B-nh0(4) + A-mh0(8); stage B k0,k1; bar; MF(0,0); bar
//   ph1: read B-nh1(4);            stage B k2,k3; bar; MF(0,1); vm4; bar
//   ph2: read A-mh1(8);            stage A k0,k1; bar; MF(1,0); bar
//   ph3:                           stage A k2,k3; bar; MF(1,1); vm2; bar
// Stage targets buf[(t+1)&1] (tile t-1's buffer, reads done) — race-free.
// Grid: 1D, bijectively XCD-chunk-swizzled (nwg % 8 == 0 for all 3 GEMMs).
template <bool RELU, bool OUT_F16>
__global__ __launch_bounds__(512, 2) void gemm_q4(
    const _Float16* __restrict__ A, const _Float16* __restrict__ W,
    const float* __restrict__ bias, void* __restrict__ Outv,
    int M, int N, int K) {
    constexpr int BM = 256, BN = 256, BK = 64;
    __shared__ __align__(16) _Float16 As[2][BM * BK];   // [256][64] f16, 2x32KB
    __shared__ __align__(16) _Float16 Bs[2][BN * BK];

    const int tid  = threadIdx.x;
    const int lane = tid & 63;
    const int rowl = lane & 15;
    const int q    = lane >> 4;          // k-chunk quarter within 64B k-slice
    const int slotx = rowl & 7;          // read-side XOR key (row&7 == rowl&7)
    const int w    = tid >> 6;           // wave 0..7
    const int wm   = (w >> 2) * 128;     // 2 waves along M
    const int wn   = (w & 3) * 64;       // 4 waves along N
    const int amId = w >> 2;             // A-half this wave consumes/stages

    // XCD-chunked bijective block swizzle (nwg % 8 == 0).
    const int nwg = gridDim.x;
    const int cpx = nwg >> 3;
    const int sw  = (blockIdx.x & 7) * cpx + (blockIdx.x >> 3);
    const int MB  = M >> 8;
    const int NB  = N >> 8;
    const int bm  = sw % MB;
    const int rr  = sw / MB;
    const int bn  = rr % NB;
    const int b   = rr / NB;

    // ---- staging constants (per-wave partition) ----
    // A-half amId (128 rows, 16KB) staged by the 4 waves with that wm:
    //   gtidA in 0..255; load k covers rows [amId*128 + k*32, +32).
    const int gtidA = (w & 3) * 64 + lane;
    const int gA    = (gtidA & 7) ^ ((gtidA >> 3) & 7);  // pre-swz src chunk
    const int rowA0 = amId * 128 + (gtidA >> 3);
    // B rows [wn, wn+64) (8KB) staged by the 2 waves with that wn:
    //   gtidB in 0..127; load k covers rows [wn + k*16, +16).
    const int gtidB = (w >> 2) * 64 + lane;
    const int gB    = (gtidB & 7) ^ ((gtidB >> 3) & 7);
    const int rowB0 = wn + (gtidB >> 3);

    const char* Ab = (const char*)(A + (size_t)b * M * K + (size_t)(bm * BM) * K);
    const char* Wb = (const char*)(W + (size_t)b * N * K + (size_t)(bn * BN) * K);
    size_t aG = ((size_t)rowA0 * K + gA * 8) * 2;   // + k*AKROW ; + tile*128B
    size_t bG = ((size_t)rowB0 * K + gB * 8) * 2;   // + k*BKROW
    const size_t AKROW = (size_t)32 * K * 2;
    const size_t BKROW = (size_t)16 * K * 2;
    // LDS dests (f16 units), linear per wave (+ lane*8 inside):
    const int ldsA0 = (amId * 1024 + (w & 3) * 64 + lane) * 8;  // + k*2048
    const int ldsB0 = (wn * 8 + (w >> 2) * 64 + lane) * 8;      // + k*1024

#define STA(BUF, KI) stage16(Ab + aG + (KI) * AKROW, &As[BUF][ldsA0 + (KI) * 2048])
#define STB(BUF, KI) stage16(Wb + bG + (KI) * BKROW, &Bs[BUF][ldsB0 + (KI) * 1024])

    f32x4 acc[8][4];
#pragma unroll
    for (int mi = 0; mi < 8; ++mi)
#pragma unroll
        for (int ni = 0; ni < 4; ++ni)
            acc[mi][ni] = (f32x4){0.f, 0.f, 0.f, 0.f};

    const int nk = K / BK;          // 8 or 16

    // prologue: stage tile 0 in wait-order (B k0..3, A k0..3), drain to 2
    // (leaves A k2,k3 in flight — not needed until ph2, drained at end-ph1).
    STB(0, 0); STB(0, 1); STB(0, 2); STB(0, 3);
    STA(0, 0); STA(0, 1); STA(0, 2); STA(0, 3);
    aG += 128; bG += 128;           // -> tile 1
    vmwait<2>();
    barrier_();

    // fragment reads: LDS f16 off = row*64 + ((ks*4+q)^(row&7))*8
#define RDA(MI0, SS)                                                          \
    _Pragma("unroll")                                                         \
    for (int m2 = 0; m2 < 4; ++m2) {                                          \
        const int ro = (wm + ((MI0) + m2) * 16 + rowl) * 64;                  \
        af[m2][0] = *(const f16x8*)(&As[SS][ro + (((0 * 4 + q) ^ slotx) * 8)]);\
        af[m2][1] = *(const f16x8*)(&As[SS][ro + (((1 * 4 + q) ^ slotx) * 8)]);\
    }
#define RDB(NI0, SS)                                                          \
    _Pragma("unroll")                                                         \
    for (int n2 = 0; n2 < 2; ++n2) {                                          \
        const int ro = (wn + ((NI0) + n2) * 16 + rowl) * 64;                  \
        bf[(NI0) + n2][0] = *(const f16x8*)(&Bs[SS][ro + (((0 * 4 + q) ^ slotx) * 8)]);\
        bf[(NI0) + n2][1] = *(const f16x8*)(&Bs[SS][ro + (((1 * 4 + q) ^ slotx) * 8)]);\
    }
#define MF(MH, NH)                                                            \
    __builtin_amdgcn_s_setprio(1);                                            \
    _Pragma("unroll")                                                         \
    for (int m2 = 0; m2 < 4; ++m2)                                            \
        _Pragma("unroll")                                                     \
        for (int n2 = 0; n2 < 2; ++n2) {                                      \
            acc[(MH)*4+m2][(NH)*2+n2] = __builtin_amdgcn_mfma_f32_16x16x32_f16(\
                af[m2][0], bf[(NH)*2+n2][0], acc[(MH)*4+m2][(NH)*2+n2], 0,0,0);\
            acc[(MH)*4+m2][(NH)*2+n2] = __builtin_amdgcn_mfma_f32_16x16x32_f16(\
                af[m2][1], bf[(NH)*2+n2][1], acc[(MH)*4+m2][(NH)*2+n2], 0,0,0);\
        }                                                                     \
    __builtin_amdgcn_s_setprio(0);

    f16x8 af[4][2], bf[4][2];

    for (int t = 0; t < nk; ++t) {
        const int cb  = t & 1;
        const int sb  = cb ^ 1;
        const bool stg = (t + 1 < nk);

        // ---- phase 0: quadrant (mh0, nh0) ----
        RDB(0, cb);
        RDA(0, cb);
        if (stg) { STB(sb, 0); STB(sb, 1); }
        barrier_();
        MF(0, 0);
        barrier_();

        // ---- phase 1: quadrant (mh0, nh1) ----
        RDB(2, cb);
        if (stg) { STB(sb, 2); STB(sb, 3); }
        barrier_();
        MF(0, 1);
        // drain prior tile's A-stages (this tile's mh1 data, >=2 phases old)
        if (stg) vmwait<4>(); else vmwait<0>();
        barrier_();

        // ---- phase 2: quadrant (mh1, nh0) ----
        RDA(4, cb);
        if (stg) { STA(sb, 0); STA(sb, 1); }
        barrier_();
        MF(1, 0);
        barrier_();

        // ---- phase 3: quadrant (mh1, nh1) ----
        if (stg) { STA(sb, 2); STA(sb, 3); }
        barrier_();
        MF(1, 1);
        // boundary: next tile's ph0/ph1 needs (B k0-3, A k0,k1) landed;
        // leave the 2 newest (A k2,k3) in flight.
        if (stg) { vmwait<2>(); }
        barrier_();
        aG += 128; bG += 128;
    }
#undef RDA
#undef RDB
#undef MF
#undef STA
#undef STB

    // epilogue: bias (+relu), store. C/D: col=lane&15, row=(lane>>4)*4+reg.
    const int qq = lane >> 4;
    float bcol[4];
    {
        const float* bp = bias + (size_t)b * N + bn * BN + wn;
#pragma unroll
        for (int ni = 0; ni < 4; ++ni) bcol[ni] = bp[ni * 16 + rowl];
    }
#pragma unroll
    for (int mi = 0; mi < 8; ++mi) {
        const int row0 = bm * BM + wm + mi * 16 + qq * 4;
#pragma unroll
        for (int r = 0; r < 4; ++r) {
            const size_t ro = (size_t)b * M * N + (size_t)(row0 + r) * N + bn * BN + wn;
#pragma unroll
            for (int ni = 0; ni < 4; ++ni) {
                float v = acc[mi][ni][r] + bcol[ni];
                if (RELU) v = fmaxf(v, 0.f);
                if (OUT_F16)
                    ((_Float16*)Outv)[ro + ni * 16 + rowl] = (_Float16)v;
                else
                    ((float*)Outv)[ro + ni * 16 + rowl] = v;
            }
        }
    }
}

// ---- legacy 2-barrier kernel, mixed f32/f16 operands (fallback path only) ----
__device__ __forceinline__ uint4 load8f32(const char* p) {
    const float4* fp = reinterpret_cast<const float4*>(p);
    float4 f0 = fp[0], f1 = fp[1];
    f16x8 o;
    o[0] = (_Float16)f0.x; o[1] = (_Float16)f0.y;
    o[2] = (_Float16)f0.z; o[3] = (_Float16)f0.w;
    o[4] = (_Float16)f1.x; o[5] = (_Float16)f1.y;
    o[6] = (_Float16)f1.z; o[7] = (_Float16)f1.w;
    return __builtin_bit_cast(uint4, o);
}

template <bool A_F16, bool W_F16, bool RELU, bool OUT_F16>
__global__ __launch_bounds__(256) void gemm_bias_act(
    const void* __restrict__ Av, const void* __restrict__ Wv,
    const float* __restrict__ bias, void* __restrict__ Outv,
    int M, int N, int K) {
    constexpr int BM = 128, BN = 128, BK = 32;
    __shared__ __align__(16) _Float16 As[BM * BK];
    __shared__ __align__(16) _Float16 Bs[BN * BK];

    const int tid  = threadIdx.x;
    const int lane = tid & 63;
    const int rowl = lane & 15;
    const int q8   = (lane >> 4) * 8;
    const int wm   = ((tid >> 6) >> 1) * 64;
    const int wn   = ((tid >> 6) & 1) * 64;
    const int bm = blockIdx.x, bn = blockIdx.y, b = blockIdx.z;

    const int c0 = tid, c1 = tid + 256;
    const int ar0 = c0 >> 2, ak0 = (c0 & 3) * 8;
    const int ar1 = c1 >> 2, ak1 = (c1 & 3) * 8;

    constexpr size_t esA = A_F16 ? 2 : 4;
    constexpr size_t esW = W_F16 ? 2 : 4;
    const char* Abase = (const char*)Av;
    const char* Wbase = (const char*)Wv;

    size_t aoff0 = ((size_t)b * M * K + (size_t)(bm * BM + ar0) * K + ak0) * esA;
    size_t aoff1 = ((size_t)b * M * K + (size_t)(bm * BM + ar1) * K + ak1) * esA;
    size_t woff0 = ((size_t)b * N * K + (size_t)(bn * BN + ar0) * K + ak0) * esW;
    size_t woff1 = ((size_t)b * N * K + (size_t)(bn * BN + ar1) * K + ak1) * esW;

    f32x4 acc[4][4];
#pragma unroll
    for (int mi = 0; mi < 4; ++mi)
#pragma unroll
        for (int ni = 0; ni < 4; ++ni)
            acc[mi][ni] = (f32x4){0.f, 0.f, 0.f, 0.f};

    const int nk = K / BK;
    for (int kk = 0; kk < nk; ++kk) {
        uint4 va0, va1, vw0, vw1;
        if (!A_F16) { va0 = load8f32(Abase + aoff0); va1 = load8f32(Abase + aoff1); }
        if (!W_F16) { vw0 = load8f32(Wbase + woff0); vw1 = load8f32(Wbase + woff1); }
        __syncthreads();
        if (A_F16) {
            stage16(Abase + aoff0, As + 8 * (size_t)c0);
            stage16(Abase + aoff1, As + 8 * (size_t)c1);
        } else {
            *(uint4*)(As + ar0 * BK + ak0) = va0;
            *(uint4*)(As + ar1 * BK + ak1) = va1;
        }
        if (W_F16) {
            stage16(Wbase + woff0, Bs + 8 * (size_t)c0);
            stage16(Wbase + woff1, Bs + 8 * (size_t)c1);
        } else {
            *(uint4*)(Bs + ar0 * BK + ak0) = vw0;
            *(uint4*)(Bs + ar1 * BK + ak1) = vw1;
        }
        aoff0 += BK * esA; aoff1 += BK * esA;
        woff0 += BK * esW; woff1 += BK * esW;
        __syncthreads();

        f16x8 af[4], bf[4];
#pragma unroll
        for (int i = 0; i < 4; ++i)
            af[i] = *(const f16x8*)(As + (wm + i * 16 + rowl) * BK + q8);
#pragma unroll
        for (int i = 0; i < 4; ++i)
            bf[i] = *(const f16x8*)(Bs + (wn + i * 16 + rowl) * BK + q8);
#pragma unroll
        for (int mi = 0; mi < 4; ++mi)
#pragma unroll
            for (int ni = 0; ni < 4; ++ni)
                acc[mi][ni] = __builtin_amdgcn_mfma_f32_16x16x32_f16(
                    af[mi], bf[ni], acc[mi][ni], 0, 0, 0);
    }

    const int q = lane >> 4;
    float bcol[4];
    {
        const float* bp = bias + (size_t)b * N + bn * BN + wn;
#pragma unroll
        for (int ni = 0; ni < 4; ++ni) bcol[ni] = bp[ni * 16 + rowl];
    }
#pragma unroll
    for (int mi = 0; mi < 4; ++mi) {
        const int row0 = bm * BM + wm + mi * 16 + q * 4;
#pragma unroll
        for (int r = 0; r < 4; ++r) {
            const size_t ro = (size_t)b * M * N + (size_t)(row0 + r) * N + bn * BN + wn;
#pragma unroll
            for (int ni = 0; ni < 4; ++ni) {
                float v = acc[mi][ni][r] + bcol[ni];
                if (RELU) v = fmaxf(v, 0.f);
                if (OUT_F16)
                    ((_Float16*)Outv)[ro + ni * 16 + rowl] = (_Float16)v;
                else
                    ((float*)Outv)[ro + ni * 16 + rowl] = v;
            }
        }
    }
}

extern "C" void kernel_launch(void* const* d_in, const int* in_sizes, int n_in,
                              void* d_out, int out_size, void* d_ws, size_t ws_size,
                              hipStream_t stream) {
    const int B = 8, S = 4096, DI = 512, DH = 1024, DO = 512;
    const float* query = (const float*)d_in[0];
    const float* W0    = (const float*)d_in[1];
    const float* b0    = (const float*)d_in[2];
    const float* W1    = (const float*)d_in[3];
    const float* b1    = (const float*)d_in[4];
    const float* W2    = (const float*)d_in[5];
    const float* b2    = (const float*)d_in[6];

    char* ws = (char*)d_ws;
    const size_t nH  = (size_t)B * S * DH;   // 33.5M
    const size_t nQ  = (size_t)B * S * DI;   // 16.8M
    const size_t nW0 = (size_t)B * DH * DI;  // 4.2M
    const size_t nW1 = (size_t)B * DH * DH;  // 8.4M
    const size_t nW2 = (size_t)B * DO * DH;  // 4.2M

    _Float16* h0 = (_Float16*)ws;             // 64 MiB
    _Float16* h1 = (_Float16*)(ws + nH * 2);  // 64 MiB
    const size_t off_casts = nH * 4;
    const size_t full_need = off_casts + (nQ + nW0 + nW1 + nW2) * 2;  // 192 MiB

    if (ws_size >= full_need) {
        _Float16* qf  = (_Float16*)(ws + off_casts);
        _Float16* w0f = qf + nQ;
        _Float16* w1f = w0f + nW0;
        _Float16* w2f = w1f + nW1;
        cast_all<<<dim3(2048), dim3(256), 0, stream>>>(
            query, qf, (int)(nQ / 4), W0, w0f, (int)(nW0 / 4),
            W1, w1f, (int)(nW1 / 4), W2, w2f, (int)(nW2 / 4));
        const dim3 blk(512);
        // 1D swizzled grids: nwg = (S/256)*(N/256)*B, divisible by 8.
        const dim3 g0(dim3((S / 256) * (DH / 256) * B));   // 512
        const dim3 g2(dim3((S / 256) * (DO / 256) * B));   // 256
        gemm_q4<true,  true ><<<g0, blk, 0, stream>>>(qf, w0f, b0, h0, S, DH, DI);
        gemm_q4<true,  true ><<<g0, blk, 0, stream>>>(h0, w1f, b1, h1, S, DH, DH);
        gemm_q4<false, false><<<g2, blk, 0, stream>>>(h1, w2f, b2, d_out, S, DO, DH);
    } else {
        const dim3 blk(256);
        const dim3 g0(S / 128, DH / 128, B);
        const dim3 g2(S / 128, DO / 128, B);
        gemm_bias_act<false, false, true,  true ><<<g0, blk, 0, stream>>>(query, W0, b0, h0, S, DH, DI);
        gemm_bias_act<true,  false, true,  true ><<<g0, blk, 0, stream>>>(h0, W1, b1, h1, S, DH, DH);
        gemm_bias_act<true,  false, false, false><<<g2, blk, 0, stream>>>(h1, W2, b2, d_out, S, DO, DH);
    }
}